// Round 6
// baseline (907.334 us; speedup 1.0000x reference)
//
#include <hip/hip_runtime.h>
#include <hip/hip_fp16.h>

#define NN 50000
#define EE 1600000

static __device__ __forceinline__ float4 f4z() { return make_float4(0.f, 0.f, 0.f, 0.f); }

// ---------------- CSR build ----------------

__global__ __launch_bounds__(256) void hist_kernel(const int* __restrict__ ei, int* __restrict__ counts)
{
    int i = blockIdx.x * blockDim.x + threadIdx.x;
    int stride = gridDim.x * blockDim.x;
    for (; i < EE; i += stride) atomicAdd(&counts[ei[EE + i]], 1);
}

__global__ __launch_bounds__(1024) void scan_kernel(const int* __restrict__ counts,
                                                    int* __restrict__ offsets,
                                                    int* __restrict__ cursor)
{
    __shared__ int wsum[16];
    __shared__ int wpre[16];
    __shared__ int carrys;
    const int t = threadIdx.x;
    const int lane = t & 63, wid = t >> 6;
    if (t == 0) carrys = 0;
    __syncthreads();
    for (int base = 0; base <= NN; base += 1024) {
        int i = base + t;
        int orig = (i < NN) ? counts[i] : 0;
        int val = orig;
        #pragma unroll
        for (int ofs = 1; ofs < 64; ofs <<= 1) {
            int n = __shfl_up(val, ofs);
            if (lane >= ofs) val += n;
        }
        if (lane == 63) wsum[wid] = val;
        __syncthreads();
        if (t < 16) {
            int w = wsum[t];
            #pragma unroll
            for (int ofs = 1; ofs < 16; ofs <<= 1) {
                int n = __shfl_up(w, ofs);
                if (t >= ofs) w += n;
            }
            wpre[t] = w;
        }
        __syncthreads();
        int carry = carrys;
        int incl = val + (wid ? wpre[wid - 1] : 0);
        int excl = incl - orig + carry;
        if (i < NN) { offsets[i] = excl; cursor[i] = excl; }
        else if (i == NN) offsets[NN] = excl;
        __syncthreads();
        if (t == 1023) carrys = carry + incl;
        __syncthreads();
    }
}

__global__ __launch_bounds__(256) void scatter_kernel(const int* __restrict__ ei,
                                                      int* __restrict__ cursor,
                                                      int* __restrict__ srcs,
                                                      int* __restrict__ posArr)
{
    int i = blockIdx.x * blockDim.x + threadIdx.x;
    int stride = gridDim.x * blockDim.x;
    for (; i < EE; i += stride) {
        int srcn = ei[i];
        int d = ei[EE + i];
        int pos = atomicAdd(&cursor[d], 1);
        srcs[pos] = srcn;
        posArr[i] = pos;
    }
}

// ---------------- ef -> fp16, permuted to dst-sorted order ----------------

__global__ __launch_bounds__(256) void efsort_kernel(const float* __restrict__ ef,
                                                     const int* __restrict__ posArr,
                                                     __half* __restrict__ efh)
{
    int idx = blockIdx.x * 256 + threadIdx.x;
    if (idx >= EE * 8) return;
    int e = idx >> 3, c = idx & 7;
    float4 v = *(const float4*)(ef + (size_t)e * 32 + 4 * c);
    int p = posArr[e];
    union { __half2 h2[2]; unsigned long long u64; } o;
    o.h2[0] = __floats2half2_rn(v.x, v.y);
    o.h2[1] = __floats2half2_rn(v.z, v.w);
    __builtin_nontemporal_store(o.u64, (unsigned long long*)(efh + (size_t)p * 32 + 4 * c));
}

// ---------------- fused q/kv(fp16)/xr projection ----------------

__global__ __launch_bounds__(256) void proj_kernel(
    const float* __restrict__ x,
    const float* __restrict__ Wq, const float* __restrict__ bq,
    const float* __restrict__ Wk, const float* __restrict__ bk,
    const float* __restrict__ Wv, const float* __restrict__ bv,
    const float* __restrict__ Ws, const float* __restrict__ bs,
    float* __restrict__ q, __half2* __restrict__ kvh,
    float* __restrict__ xr)
{
    __shared__ float xs[32][128];
    const int tid = threadIdx.x;
    const int row0 = blockIdx.x * 32;
    for (int i = tid; i < 1024; i += 256) {
        int r = i >> 5, c4 = i & 31;
        int gr = row0 + r;
        float4 val = f4z();
        if (gr < NN) val = ((const float4*)(x + (size_t)gr * 128))[c4];
        ((float4*)xs[r])[c4] = val;
    }
    __syncthreads();
    const int cg = tid & 31;
    const int rg = tid >> 5;
    float4 aq[4], ak[4], av[4], as_[4];
    #pragma unroll
    for (int r = 0; r < 4; ++r) { aq[r] = f4z(); ak[r] = f4z(); av[r] = f4z(); as_[r] = f4z(); }
    #pragma unroll 2
    for (int kk = 0; kk < 128; ++kk) {
        float4 wq = ((const float4*)(Wq + kk * 128))[cg];
        float4 wk = ((const float4*)(Wk + kk * 128))[cg];
        float4 wv = ((const float4*)(Wv + kk * 128))[cg];
        float4 ws = ((const float4*)(Ws + kk * 128))[cg];
        #pragma unroll
        for (int r = 0; r < 4; ++r) {
            float xv = xs[4 * rg + r][kk];
            aq[r].x += xv * wq.x; aq[r].y += xv * wq.y; aq[r].z += xv * wq.z; aq[r].w += xv * wq.w;
            ak[r].x += xv * wk.x; ak[r].y += xv * wk.y; ak[r].z += xv * wk.z; ak[r].w += xv * wk.w;
            av[r].x += xv * wv.x; av[r].y += xv * wv.y; av[r].z += xv * wv.z; av[r].w += xv * wv.w;
            as_[r].x += xv * ws.x; as_[r].y += xv * ws.y; as_[r].z += xv * ws.z; as_[r].w += xv * ws.w;
        }
    }
    const float4 bq4 = ((const float4*)bq)[cg];
    const float4 bk4 = ((const float4*)bk)[cg];
    const float4 bv4 = ((const float4*)bv)[cg];
    const float4 bs4 = ((const float4*)bs)[cg];
    #pragma unroll
    for (int r = 0; r < 4; ++r) {
        int gr = row0 + 4 * rg + r;
        if (gr >= NN) continue;
        float4 o;
        o.x = aq[r].x + bq4.x; o.y = aq[r].y + bq4.y; o.z = aq[r].z + bq4.z; o.w = aq[r].w + bq4.w;
        ((float4*)(q + (size_t)gr * 128))[cg] = o;
        float kx = ak[r].x + bk4.x, ky = ak[r].y + bk4.y, kz = ak[r].z + bk4.z, kw = ak[r].w + bk4.w;
        float vx = av[r].x + bv4.x, vy = av[r].y + bv4.y, vz = av[r].z + bv4.z, vw = av[r].w + bv4.w;
        union { __half2 h2[4]; float4 f4; } up;
        up.h2[0] = __floats2half2_rn(kx, vx);
        up.h2[1] = __floats2half2_rn(ky, vy);
        up.h2[2] = __floats2half2_rn(kz, vz);
        up.h2[3] = __floats2half2_rn(kw, vw);
        *((float4*)(kvh + (size_t)gr * 128 + 4 * cg)) = up.f4;
        o.x = as_[r].x + bs4.x; o.y = as_[r].y + bs4.y; o.z = as_[r].z + bs4.z; o.w = as_[r].w + bs4.w;
        ((float4*)(xr + (size_t)gr * 128))[cg] = o;
    }
}

// ---------------- qe[n, h*32+d] (fp16 out) ----------------

__global__ __launch_bounds__(256) void qe_small(const float* __restrict__ q,
                                                const float* __restrict__ We,
                                                __half* __restrict__ qeh)
{
    int idx = blockIdx.x * 256 + threadIdx.x;
    if (idx >= NN * 64) return;
    int n = idx >> 6, r = idx & 63;
    int h = r >> 3, d0 = (r & 7) << 2;
    const float* qrow = q + (size_t)n * 128 + h * 16;
    float acc0 = 0.f, acc1 = 0.f, acc2 = 0.f, acc3 = 0.f;
    #pragma unroll
    for (int c = 0; c < 4; ++c) {
        float4 qf = *(const float4*)(qrow + 4 * c);
        float4 w0 = *(const float4*)(We + (d0 + 0) * 128 + h * 16 + 4 * c);
        float4 w1 = *(const float4*)(We + (d0 + 1) * 128 + h * 16 + 4 * c);
        float4 w2 = *(const float4*)(We + (d0 + 2) * 128 + h * 16 + 4 * c);
        float4 w3 = *(const float4*)(We + (d0 + 3) * 128 + h * 16 + 4 * c);
        acc0 += qf.x * w0.x + qf.y * w0.y + qf.z * w0.z + qf.w * w0.w;
        acc1 += qf.x * w1.x + qf.y * w1.y + qf.z * w1.z + qf.w * w1.w;
        acc2 += qf.x * w2.x + qf.y * w2.y + qf.z * w2.z + qf.w * w2.w;
        acc3 += qf.x * w3.x + qf.y * w3.y + qf.z * w3.z + qf.w * w3.w;
    }
    union { __half2 h2[2]; float2 f2; } u;
    u.h2[0] = __floats2half2_rn(acc0, acc1);
    u.h2[1] = __floats2half2_rn(acc2, acc3);
    *(float2*)(qeh + (size_t)n * 256 + h * 32 + d0) = u.f2;
}

// ---------------- fused attention + beta-skip + LN1 + relu ----------------

__global__ __launch_bounds__(256) void attn_kernel(
    const __half* __restrict__ efh,
    const float* __restrict__ We, const float* __restrict__ be,
    const float* __restrict__ q, const __half* __restrict__ qeh,
    const __half2* __restrict__ kvh,
    const float* __restrict__ xr, const float* __restrict__ x,
    const float* __restrict__ Wbeta,
    const float* __restrict__ ln1g, const float* __restrict__ ln1b,
    const int* __restrict__ offsets, const int* __restrict__ srcs,
    float* __restrict__ h, float* __restrict__ colsum)
{
    __shared__ float WeS[32][128];
    __shared__ float cs[4][128];
    const int tid = threadIdx.x;
    for (int i = tid; i < 4096; i += 256) ((float*)WeS)[i] = We[i];
    const int lane = tid & 63;
    const int wid = tid >> 6;
    const int f0 = 2 * lane;
    const int l8 = lane & 7;
    const int grp = lane & 56;

    const float be0 = be[f0], be1 = be[f0 + 1];
    const float wbo0 = Wbeta[f0],       wbo1 = Wbeta[f0 + 1];
    const float wbr0 = Wbeta[128 + f0], wbr1 = Wbeta[128 + f0 + 1];
    const float wbd0 = Wbeta[256 + f0], wbd1 = Wbeta[256 + f0 + 1];
    const float lg0 = ln1g[f0], lg1 = ln1g[f0 + 1];
    const float lb0 = ln1b[f0], lb1 = ln1b[f0 + 1];

    cs[wid][f0] = 0.f; cs[wid][f0 + 1] = 0.f;
    __syncthreads();

    const int gwave = blockIdx.x * 4 + wid;
    const int nwave = gridDim.x * 4;

    for (int node = gwave; node < NN; node += nwave) {
        const int beg = offsets[node];
        const int end = offsets[node + 1];
        const float2 qv = *(const float2*)(q + (size_t)node * 128 + f0);
        union { float2 f2; __half2 h2[2]; } uq;
        uq.f2 = *(const float2*)(qeh + (size_t)node * 256 + 4 * lane);
        const float2 qe01 = __half22float2(uq.h2[0]);
        const float2 qe23 = __half22float2(uq.h2[1]);
        const float4 qev = make_float4(qe01.x, qe01.y, qe23.x, qe23.y);
        float qbe = qv.x * be0 + qv.y * be1;
        qbe += __shfl_xor(qbe, 1); qbe += __shfl_xor(qbe, 2); qbe += __shfl_xor(qbe, 4);
        const float qbe25 = qbe * 0.25f;

        float m = -1e30f, s = 0.f, a0 = 0.f, a1 = 0.f;
        float4 wef = f4z();

        if (beg < end) {
            int srcC[8], srcN[8];
            {
                int cn = end - beg;
                #pragma unroll
                for (int u = 0; u < 8; ++u) srcC[u] = srcs[beg + (u < cn ? u : cn - 1)];
            }
            for (int t = beg; t < end; t += 8) {
                const int cnt = end - t;
                // ---- gathers: kv by src (L3-hot), ef sequential (streaming, nt) ----
                float2 kvraw[8]; unsigned long long efraw[8];
                #pragma unroll
                for (int u = 0; u < 8; ++u) {
                    kvraw[u] = *(const float2*)(kvh + (size_t)srcC[u] * 128 + f0);
                    int row = t + u; if (row >= end) row = end - 1;
                    efraw[u] = __builtin_nontemporal_load(
                        (const unsigned long long*)(efh + (size_t)row * 32 + 4 * l8));
                }
                // ---- prefetch next batch's src indices ----
                const int tn = t + 8;
                if (tn < end) {
                    int cn = end - tn;
                    #pragma unroll
                    for (int u = 0; u < 8; ++u) srcN[u] = srcs[tn + (u < cn ? u : cn - 1)];
                }
                // ---- logits (parallel across 8 edges) + unpack ----
                float lgt[8]; float2 vfl[8]; float4 efv[8];
                #pragma unroll
                for (int u = 0; u < 8; ++u) {
                    union { unsigned long long u64; __half2 h2[2]; } ue; ue.u64 = efraw[u];
                    float2 e01 = __half22float2(ue.h2[0]);
                    float2 e23 = __half22float2(ue.h2[1]);
                    efv[u] = make_float4(e01.x, e01.y, e23.x, e23.y);
                    union { float2 f2; __half2 h2[2]; } uk; uk.f2 = kvraw[u];
                    float2 k0v0 = __half22float2(uk.h2[0]);
                    float2 k1v1 = __half22float2(uk.h2[1]);
                    vfl[u] = make_float2(k0v0.y, k1v1.y);
                    float part = qv.x * k0v0.x + qv.y * k1v1.x
                               + qev.x * efv[u].x + qev.y * efv[u].y
                               + qev.z * efv[u].z + qev.w * efv[u].w;
                    part += __shfl_xor(part, 1);
                    part += __shfl_xor(part, 2);
                    part += __shfl_xor(part, 4);
                    lgt[u] = (u < cnt) ? (part * 0.25f + qbe25) : -1e30f;
                }
                // ---- batch tree combine ----
                float m01 = fmaxf(lgt[0], lgt[1]), m23 = fmaxf(lgt[2], lgt[3]);
                float m45 = fmaxf(lgt[4], lgt[5]), m67 = fmaxf(lgt[6], lgt[7]);
                float bm = fmaxf(fmaxf(m01, m23), fmaxf(m45, m67));
                float p[8];
                #pragma unroll
                for (int u = 0; u < 8; ++u) p[u] = __expf(lgt[u] - bm);
                float bsA = 0.f, bsB = 0.f, b0A = 0.f, b0B = 0.f, b1A = 0.f, b1B = 0.f;
                float4 befA = f4z(), befB = f4z();
                #pragma unroll
                for (int u = 0; u < 8; u += 2) {
                    bsA += p[u];     bsB += p[u + 1];
                    b0A = fmaf(p[u], vfl[u].x, b0A);       b0B = fmaf(p[u + 1], vfl[u + 1].x, b0B);
                    b1A = fmaf(p[u], vfl[u].y, b1A);       b1B = fmaf(p[u + 1], vfl[u + 1].y, b1B);
                    befA.x = fmaf(p[u], efv[u].x, befA.x); befB.x = fmaf(p[u + 1], efv[u + 1].x, befB.x);
                    befA.y = fmaf(p[u], efv[u].y, befA.y); befB.y = fmaf(p[u + 1], efv[u + 1].y, befB.y);
                    befA.z = fmaf(p[u], efv[u].z, befA.z); befB.z = fmaf(p[u + 1], efv[u + 1].z, befB.z);
                    befA.w = fmaf(p[u], efv[u].w, befA.w); befB.w = fmaf(p[u + 1], efv[u + 1].w, befB.w);
                }
                // ---- single merge into running state ----
                const float nm = fmaxf(m, bm);
                const float so = __expf(m - nm);
                const float sn = __expf(bm - nm);
                s  = s  * so + (bsA + bsB) * sn;
                a0 = a0 * so + (b0A + b0B) * sn;
                a1 = a1 * so + (b1A + b1B) * sn;
                wef.x = wef.x * so + (befA.x + befB.x) * sn;
                wef.y = wef.y * so + (befA.y + befB.y) * sn;
                wef.z = wef.z * so + (befA.z + befB.z) * sn;
                wef.w = wef.w * so + (befA.w + befB.w) * sn;
                m = nm;
                #pragma unroll
                for (int u = 0; u < 8; ++u) srcC[u] = srcN[u];
            }
        }

        const float inv = 1.f / (s + 1e-16f);
        float o0 = fmaf(a0, inv, be0);
        float o1 = fmaf(a1, inv, be1);
        float wn0 = wef.x * inv, wn1 = wef.y * inv, wn2 = wef.z * inv, wn3 = wef.w * inv;
        float ew0 = 0.f, ew1 = 0.f;
        #pragma unroll
        for (int l2 = 0; l2 < 8; ++l2) {
            float b0 = __shfl(wn0, grp + l2);
            float b1 = __shfl(wn1, grp + l2);
            float b2 = __shfl(wn2, grp + l2);
            float b3 = __shfl(wn3, grp + l2);
            float2 w0 = *(const float2*)&WeS[4 * l2 + 0][f0];
            float2 w1 = *(const float2*)&WeS[4 * l2 + 1][f0];
            float2 w2 = *(const float2*)&WeS[4 * l2 + 2][f0];
            float2 w3 = *(const float2*)&WeS[4 * l2 + 3][f0];
            ew0 += b0 * w0.x + b1 * w1.x + b2 * w2.x + b3 * w3.x;
            ew1 += b0 * w0.y + b1 * w1.y + b2 * w2.y + b3 * w3.y;
        }
        o0 += ew0; o1 += ew1;
        if (end == beg) { o0 = 0.f; o1 = 0.f; }

        const float2 xrv = *(const float2*)(xr + (size_t)node * 128 + f0);
        float bp = o0 * wbo0 + o1 * wbo1 + xrv.x * wbr0 + xrv.y * wbr1
                 + (o0 - xrv.x) * wbd0 + (o1 - xrv.y) * wbd1;
        #pragma unroll
        for (int msk = 1; msk < 64; msk <<= 1) bp += __shfl_xor(bp, msk);
        const float beta = 1.f / (1.f + __expf(-bp));
        const float2 xv = *(const float2*)(x + (size_t)node * 128 + f0);
        float t0 = beta * xrv.x + (1.f - beta) * o0 + xv.x;
        float t1 = beta * xrv.y + (1.f - beta) * o1 + xv.y;
        float sm = t0 + t1, sq = t0 * t0 + t1 * t1;
        #pragma unroll
        for (int msk = 1; msk < 64; msk <<= 1) { sm += __shfl_xor(sm, msk); sq += __shfl_xor(sq, msk); }
        const float mu = sm * (1.f / 128.f);
        const float var = sq * (1.f / 128.f) - mu * mu;
        const float rstd = rsqrtf(var + 1e-5f);
        const float h0 = fmaxf((t0 - mu) * rstd * lg0 + lb0, 0.f);
        const float h1 = fmaxf((t1 - mu) * rstd * lg1 + lb1, 0.f);
        *(float2*)(h + (size_t)node * 128 + f0) = make_float2(h0, h1);
        cs[wid][f0] += h0; cs[wid][f0 + 1] += h1;
    }
    __syncthreads();
    if (wid == 0) {
        float c0 = cs[0][f0] + cs[1][f0] + cs[2][f0] + cs[3][f0];
        float c1 = cs[0][f0 + 1] + cs[1][f0 + 1] + cs[2][f0 + 1] + cs[3][f0 + 1];
        atomicAdd(&colsum[f0], c0);
        atomicAdd(&colsum[f0 + 1], c1);
    }
}

// ---------------- global context: 1024 threads, 8-slice matvecs ----------------

__global__ __launch_bounds__(1024) void gctx_kernel(
    const float* __restrict__ colsum,
    const float* __restrict__ Wr, const float* __restrict__ br,
    const float* __restrict__ Ww, const float* __restrict__ bw,
    const float* __restrict__ Wg, const float* __restrict__ bg,
    float* __restrict__ gc)
{
    __shared__ float hm[128], g[128], gb[128];
    __shared__ float red[8][128];
    const int t = threadIdx.x, f = t & 127, sl = t >> 7;
    if (sl == 0) hm[f] = colsum[f] * (1.f / (float)NN);
    __syncthreads();
    float a = 0.f;
    #pragma unroll
    for (int j = 0; j < 16; ++j) { int i = sl * 16 + j; a += hm[i] * Wr[i * 128 + f]; }
    red[sl][f] = a;
    __syncthreads();
    if (sl == 0) {
        float s = br[f];
        #pragma unroll
        for (int j = 0; j < 8; ++j) s += red[j][f];
        g[f] = fmaxf(s, 0.f);
    }
    __syncthreads();
    a = 0.f;
    #pragma unroll
    for (int j = 0; j < 16; ++j) { int i = sl * 16 + j; a += g[i] * Ww[i * 128 + f]; }
    red[sl][f] = a;
    __syncthreads();
    if (sl == 0) {
        float s = bw[f];
        #pragma unroll
        for (int j = 0; j < 8; ++j) s += red[j][f];
        gb[f] = s;
        gc[f] = s;
    }
    __syncthreads();
    a = 0.f;
    #pragma unroll
    for (int j = 0; j < 16; ++j) { int i = sl * 16 + j; a += gb[i] * Wg[(128 + i) * 128 + f]; }
    red[sl][f] = a;
    __syncthreads();
    if (sl == 0) {
        float s = bg[f];
        #pragma unroll
        for (int j = 0; j < 8; ++j) s += red[j][f];
        gc[128 + f] = s;
    }
}

// ---------------- final: h@Wg[:128] + gate + LN2 fused ----------------

__global__ __launch_bounds__(256) void final_kernel(
    const float* __restrict__ h, const float* __restrict__ Wg,
    const float* __restrict__ gc,
    const float* __restrict__ ln2g, const float* __restrict__ ln2b,
    float* __restrict__ out)
{
    __shared__ float hs[32][128];
    __shared__ float ys[32][128];
    const int tid = threadIdx.x;
    const int row0 = blockIdx.x * 32;
    for (int i = tid; i < 1024; i += 256) {
        int r = i >> 5, c4 = i & 31;
        int gr = row0 + r;
        float4 val = f4z();
        if (gr < NN) val = ((const float4*)(h + (size_t)gr * 128))[c4];
        ((float4*)hs[r])[c4] = val;
    }
    __syncthreads();
    const int cg = tid & 31;
    const int rg = tid >> 5;
    float4 a[4];
    #pragma unroll
    for (int r = 0; r < 4; ++r) a[r] = f4z();
    #pragma unroll 2
    for (int kk = 0; kk < 128; ++kk) {
        float4 w4 = ((const float4*)(Wg + kk * 128))[cg];
        #pragma unroll
        for (int r = 0; r < 4; ++r) {
            float xv = hs[4 * rg + r][kk];
            a[r].x += xv * w4.x; a[r].y += xv * w4.y; a[r].z += xv * w4.z; a[r].w += xv * w4.w;
        }
    }
    const float4 gb = ((const float4*)gc)[cg];
    const float4 c2 = ((const float4*)(gc + 128))[cg];
    #pragma unroll
    for (int r = 0; r < 4; ++r) {
        int row = 4 * rg + r;
        float4 hv = ((float4*)hs[row])[cg];
        float4 y;
        float gx;
        gx = 1.f / (1.f + __expf(-(a[r].x + c2.x))); y.x = hv.x + gx * gb.x;
        gx = 1.f / (1.f + __expf(-(a[r].y + c2.y))); y.y = hv.y + gx * gb.y;
        gx = 1.f / (1.f + __expf(-(a[r].z + c2.z))); y.z = hv.z + gx * gb.z;
        gx = 1.f / (1.f + __expf(-(a[r].w + c2.w))); y.w = hv.w + gx * gb.w;
        ((float4*)ys[row])[cg] = y;
    }
    __syncthreads();
    const int lane = tid & 63;
    const int wid = tid >> 6;
    const int f0 = 2 * lane;
    const float lg0 = ln2g[f0], lg1 = ln2g[f0 + 1];
    const float lb0 = ln2b[f0], lb1 = ln2b[f0 + 1];
    for (int rr = 0; rr < 8; ++rr) {
        int row = wid * 8 + rr;
        int gr = row0 + row;
        if (gr >= NN) continue;
        float y0 = ys[row][f0], y1 = ys[row][f0 + 1];
        float sm = y0 + y1, sq = y0 * y0 + y1 * y1;
        #pragma unroll
        for (int msk = 1; msk < 64; msk <<= 1) { sm += __shfl_xor(sm, msk); sq += __shfl_xor(sq, msk); }
        float mu = sm * (1.f / 128.f);
        float var = sq * (1.f / 128.f) - mu * mu;
        float rstd = rsqrtf(var + 1e-5f);
        float o0 = (y0 - mu) * rstd * lg0 + lb0;
        float o1 = (y1 - mu) * rstd * lg1 + lb1;
        *(float2*)(out + (size_t)gr * 128 + f0) = make_float2(o0, o1);
    }
}

// ---------------- launch ----------------

extern "C" void kernel_launch(void* const* d_in, const int* in_sizes, int n_in,
                              void* d_out, int out_size, void* d_ws, size_t ws_size,
                              hipStream_t stream)
{
    const float* x    = (const float*)d_in[0];
    const int*   ei   = (const int*)d_in[1];
    const float* ef   = (const float*)d_in[2];
    const float* Wq   = (const float*)d_in[3];
    const float* bq   = (const float*)d_in[4];
    const float* Wk   = (const float*)d_in[5];
    const float* bk   = (const float*)d_in[6];
    const float* Wv   = (const float*)d_in[7];
    const float* bv   = (const float*)d_in[8];
    const float* We   = (const float*)d_in[9];
    const float* be   = (const float*)d_in[10];
    const float* Wsk  = (const float*)d_in[11];
    const float* bsk  = (const float*)d_in[12];
    const float* Wbeta= (const float*)d_in[13];
    const float* g1   = (const float*)d_in[14];
    const float* b1   = (const float*)d_in[15];
    const float* Wr   = (const float*)d_in[16];
    const float* br   = (const float*)d_in[17];
    const float* Ww   = (const float*)d_in[18];
    const float* bw   = (const float*)d_in[19];
    const float* Wg   = (const float*)d_in[20];
    const float* bg   = (const float*)d_in[21];
    const float* g2   = (const float*)d_in[22];
    const float* b2   = (const float*)d_in[23];
    float* out = (float*)d_out;

    const size_t NF = (size_t)NN * 128;
    float* q      = (float*)d_ws;
    float* xr     = q + NF;
    float* h      = xr + NF;
    __half2* kvh  = (__half2*)(h + NF);       // NN*128 half2 = NF floats
    __half* qeh   = (__half*)(kvh + NF);      // NN*256 half  = NF floats
    __half* efh   = (__half*)(qeh + (size_t)NN * 256);   // EE*32 half = 102.4 MB
    float* colsum = (float*)(efh + (size_t)EE * 32);
    float* gc     = colsum + 128;             // 256 floats
    int* counts   = (int*)(gc + 256);
    int* offsets  = counts + NN;              // NN+2 (pad)
    int* cursor   = offsets + NN + 2;
    int* srcs     = cursor + NN;              // EE ints
    int* posArr   = srcs + EE;                // EE ints

    hipMemsetAsync(counts, 0, NN * sizeof(int), stream);
    hipMemsetAsync(colsum, 0, 128 * sizeof(float), stream);

    hist_kernel<<<2048, 256, 0, stream>>>(ei, counts);
    scan_kernel<<<1, 1024, 0, stream>>>(counts, offsets, cursor);
    scatter_kernel<<<2048, 256, 0, stream>>>(ei, cursor, srcs, posArr);
    efsort_kernel<<<(EE * 8 + 255) / 256, 256, 0, stream>>>(ef, posArr, efh);
    proj_kernel<<<(NN + 31) / 32, 256, 0, stream>>>(x, Wq, bq, Wk, bk, Wv, bv, Wsk, bsk, q, kvh, xr);
    qe_small<<<(NN * 64 + 255) / 256, 256, 0, stream>>>(q, We, qeh);
    attn_kernel<<<2048, 256, 0, stream>>>(efh, We, be, q, qeh, kvh, xr, x, Wbeta, g1, b1,
                                          offsets, srcs, h, colsum);
    gctx_kernel<<<1, 1024, 0, stream>>>(colsum, Wr, br, Ww, bw, Wg, bg, gc);
    final_kernel<<<(NN + 31) / 32, 256, 0, stream>>>(h, Wg, gc, g2, b2, out);
}

// Round 7
// 739.614 us; speedup vs baseline: 1.2268x; 1.2268x over previous
//
#include <hip/hip_runtime.h>
#include <hip/hip_fp16.h>

#define NN 50000
#define EE 1600000
#define NB_HIST 1024
#define NB_PROJ 1563   // ceil(NN/32)

typedef float f4v __attribute__((ext_vector_type(4)));

static __device__ __forceinline__ float4 f4z() { return make_float4(0.f, 0.f, 0.f, 0.f); }

// ---------------- scan ----------------

__global__ __launch_bounds__(1024) void scan_kernel(const int* __restrict__ counts,
                                                    int* __restrict__ offsets,
                                                    int* __restrict__ cursor)
{
    __shared__ int wsum[16];
    __shared__ int wpre[16];
    __shared__ int carrys;
    const int t = threadIdx.x;
    const int lane = t & 63, wid = t >> 6;
    if (t == 0) carrys = 0;
    __syncthreads();
    for (int base = 0; base <= NN; base += 1024) {
        int i = base + t;
        int orig = (i < NN) ? counts[i] : 0;
        int val = orig;
        #pragma unroll
        for (int ofs = 1; ofs < 64; ofs <<= 1) {
            int n = __shfl_up(val, ofs);
            if (lane >= ofs) val += n;
        }
        if (lane == 63) wsum[wid] = val;
        __syncthreads();
        if (t < 16) {
            int w = wsum[t];
            #pragma unroll
            for (int ofs = 1; ofs < 16; ofs <<= 1) {
                int n = __shfl_up(w, ofs);
                if (t >= ofs) w += n;
            }
            wpre[t] = w;
        }
        __syncthreads();
        int carry = carrys;
        int incl = val + (wid ? wpre[wid - 1] : 0);
        int excl = incl - orig + carry;
        if (i < NN) { offsets[i] = excl; cursor[i] = excl; }
        else if (i == NN) offsets[NN] = excl;
        __syncthreads();
        if (t == 1023) carrys = carry + incl;
        __syncthreads();
    }
}

__global__ __launch_bounds__(256) void scatter_kernel(const int* __restrict__ ei,
                                                      int* __restrict__ cursor,
                                                      int2* __restrict__ sorted2)
{
    int i = blockIdx.x * blockDim.x + threadIdx.x;
    int stride = gridDim.x * blockDim.x;
    for (; i < EE; i += stride) {
        int srcn = ei[i];
        int d = ei[EE + i];
        int pos = atomicAdd(&cursor[d], 1);
        sorted2[pos] = make_int2(i, srcn);
    }
    if (blockIdx.x == 0 && threadIdx.x < 16) sorted2[EE + threadIdx.x] = make_int2(0, 0);
}

// ---------------- K1: hist (blocks < NB_HIST) + proj/qe (rest) ----------------

__global__ __launch_bounds__(256) void k1_kernel(
    const int* __restrict__ ei, int* __restrict__ counts,
    const float* __restrict__ x,
    const float* __restrict__ Wq, const float* __restrict__ bq,
    const float* __restrict__ Wk, const float* __restrict__ bk,
    const float* __restrict__ Wv, const float* __restrict__ bv,
    const float* __restrict__ Ws, const float* __restrict__ bs,
    const float* __restrict__ We,
    float* __restrict__ q, __half2* __restrict__ kvh,
    float* __restrict__ xr, __half* __restrict__ qeh)
{
    const int tid = threadIdx.x;
    if (blockIdx.x < NB_HIST) {
        int i = blockIdx.x * 256 + tid;
        int stride = NB_HIST * 256;
        for (; i < EE; i += stride) atomicAdd(&counts[ei[EE + i]], 1);
        return;
    }
    __shared__ float xs[32][132];
    __shared__ float WeS[32 * 129];
    const int row0 = (blockIdx.x - NB_HIST) * 32;
    for (int i = tid; i < 4096; i += 256) WeS[(i >> 7) * 129 + (i & 127)] = We[i];
    for (int i = tid; i < 1024; i += 256) {
        int r = i >> 5, c4 = i & 31;
        int gr = row0 + r;
        float4 val = f4z();
        if (gr < NN) val = ((const float4*)(x + (size_t)gr * 128))[c4];
        ((float4*)xs[r])[c4] = val;
    }
    __syncthreads();
    const int cg = tid & 31;
    const int rg = tid >> 5;
    float4 aq[4], ak[4], av[4], as_[4];
    #pragma unroll
    for (int r = 0; r < 4; ++r) { aq[r] = f4z(); ak[r] = f4z(); av[r] = f4z(); as_[r] = f4z(); }
    #pragma unroll 2
    for (int kk = 0; kk < 128; ++kk) {
        float4 wq = ((const float4*)(Wq + kk * 128))[cg];
        float4 wk = ((const float4*)(Wk + kk * 128))[cg];
        float4 wv = ((const float4*)(Wv + kk * 128))[cg];
        float4 ws = ((const float4*)(Ws + kk * 128))[cg];
        #pragma unroll
        for (int r = 0; r < 4; ++r) {
            float xv = xs[4 * rg + r][kk];
            aq[r].x += xv * wq.x; aq[r].y += xv * wq.y; aq[r].z += xv * wq.z; aq[r].w += xv * wq.w;
            ak[r].x += xv * wk.x; ak[r].y += xv * wk.y; ak[r].z += xv * wk.z; ak[r].w += xv * wk.w;
            av[r].x += xv * wv.x; av[r].y += xv * wv.y; av[r].z += xv * wv.z; av[r].w += xv * wv.w;
            as_[r].x += xv * ws.x; as_[r].y += xv * ws.y; as_[r].z += xv * ws.z; as_[r].w += xv * ws.w;
        }
    }
    const float4 bq4 = ((const float4*)bq)[cg];
    const float4 bk4 = ((const float4*)bk)[cg];
    const float4 bv4 = ((const float4*)bv)[cg];
    const float4 bs4 = ((const float4*)bs)[cg];
    __syncthreads();   // all GEMM reads of xs done before q overwrites it
    #pragma unroll
    for (int r = 0; r < 4; ++r) {
        int gr = row0 + 4 * rg + r;
        if (gr >= NN) continue;
        float4 o;
        o.x = aq[r].x + bq4.x; o.y = aq[r].y + bq4.y; o.z = aq[r].z + bq4.z; o.w = aq[r].w + bq4.w;
        ((float4*)(q + (size_t)gr * 128))[cg] = o;
        ((float4*)xs[4 * rg + r])[cg] = o;    // stash q tile for qe phase
        float kx = ak[r].x + bk4.x, ky = ak[r].y + bk4.y, kz = ak[r].z + bk4.z, kw = ak[r].w + bk4.w;
        float vx = av[r].x + bv4.x, vy = av[r].y + bv4.y, vz = av[r].z + bv4.z, vw = av[r].w + bv4.w;
        union { __half2 h2[4]; float4 f4; } up;
        up.h2[0] = __floats2half2_rn(kx, vx);
        up.h2[1] = __floats2half2_rn(ky, vy);
        up.h2[2] = __floats2half2_rn(kz, vz);
        up.h2[3] = __floats2half2_rn(kw, vw);
        *((float4*)(kvh + (size_t)gr * 128 + 4 * cg)) = up.f4;
        o.x = as_[r].x + bs4.x; o.y = as_[r].y + bs4.y; o.z = as_[r].z + bs4.z; o.w = as_[r].w + bs4.w;
        ((float4*)(xr + (size_t)gr * 128))[cg] = o;
    }
    __syncthreads();
    // qe phase: qe[n, h*32+d] = sum_c q[n, h*16+c] * We[d, h*16+c]
    const int row = tid >> 3;      // 0..31
    const int j = tid & 7;         // 0..7 -> d = j*4..j*4+3
    const int gr2 = row0 + row;
    if (gr2 < NN) {
        const float* xrow = xs[row];
        #pragma unroll
        for (int hh = 0; hh < 8; ++hh) {
            float a0 = 0.f, a1 = 0.f, a2 = 0.f, a3 = 0.f;
            #pragma unroll
            for (int c = 0; c < 16; ++c) {
                float qv = xrow[hh * 16 + c];
                const float* wb = &WeS[(j * 4) * 129 + hh * 16 + c];
                a0 += qv * wb[0];
                a1 += qv * wb[129];
                a2 += qv * wb[258];
                a3 += qv * wb[387];
            }
            union { __half2 h2[2]; unsigned long long u64; } u;
            u.h2[0] = __floats2half2_rn(a0, a1);
            u.h2[1] = __floats2half2_rn(a2, a3);
            *(unsigned long long*)(qeh + (size_t)gr2 * 256 + hh * 32 + j * 4) = u.u64;
        }
    }
}

// ---------------- fused attention + beta-skip + LN1 + relu ----------------

__global__ __launch_bounds__(256) void attn_kernel(
    const float* __restrict__ efeat,
    const float* __restrict__ We, const float* __restrict__ be,
    const float* __restrict__ q, const __half* __restrict__ qeh,
    const __half2* __restrict__ kvh,
    const float* __restrict__ xr, const float* __restrict__ x,
    const float* __restrict__ Wbeta,
    const float* __restrict__ ln1g, const float* __restrict__ ln1b,
    const int* __restrict__ offsets, const int2* __restrict__ sorted2,
    float* __restrict__ h, float* __restrict__ colsum)
{
    __shared__ float WeS[32][128];
    __shared__ float cs[4][128];
    const int tid = threadIdx.x;
    for (int i = tid; i < 4096; i += 256) ((float*)WeS)[i] = We[i];
    const int lane = tid & 63;
    const int wid = tid >> 6;
    const int f0 = 2 * lane;
    const int l8 = lane & 7;
    const int grp = lane & 56;

    const float be0 = be[f0], be1 = be[f0 + 1];
    const float wbo0 = Wbeta[f0],       wbo1 = Wbeta[f0 + 1];
    const float wbr0 = Wbeta[128 + f0], wbr1 = Wbeta[128 + f0 + 1];
    const float wbd0 = Wbeta[256 + f0], wbd1 = Wbeta[256 + f0 + 1];
    const float lg0 = ln1g[f0], lg1 = ln1g[f0 + 1];
    const float lb0 = ln1b[f0], lb1 = ln1b[f0 + 1];

    cs[wid][f0] = 0.f; cs[wid][f0 + 1] = 0.f;
    __syncthreads();

    const int gwave = blockIdx.x * 4 + wid;
    const int nwave = gridDim.x * 4;

    for (int node = gwave; node < NN; node += nwave) {
        const int beg = offsets[node];
        const int end = offsets[node + 1];
        const float2 qv = *(const float2*)(q + (size_t)node * 128 + f0);
        union { float2 f2; __half2 h2[2]; } uq;
        uq.f2 = *(const float2*)(qeh + (size_t)node * 256 + 4 * lane);
        const float2 qe01 = __half22float2(uq.h2[0]);
        const float2 qe23 = __half22float2(uq.h2[1]);
        const float4 qev = make_float4(qe01.x, qe01.y, qe23.x, qe23.y);
        float qbe = qv.x * be0 + qv.y * be1;
        qbe += __shfl_xor(qbe, 1); qbe += __shfl_xor(qbe, 2); qbe += __shfl_xor(qbe, 4);
        const float qbe25 = qbe * 0.25f;

        float m = -1e30f, s = 0.f, a0 = 0.f, a1 = 0.f;
        float4 wef = f4z();

        if (beg < end) {
            int2 es[8], esn[8];
            #pragma unroll
            for (int u = 0; u < 8; ++u) es[u] = sorted2[beg + u];   // pad16 makes this safe
            for (int t = beg; t < end; t += 8) {
                const int cnt = end - t;
                // ---- gathers: ef nontemporal (read-once stream), kv cached ----
                f4v efv[8]; float2 kvraw[8];
                #pragma unroll
                for (int u = 0; u < 8; ++u) {
                    efv[u] = __builtin_nontemporal_load(
                        (const f4v*)(efeat + (size_t)es[u].x * 32 + 4 * l8));
                    kvraw[u] = *(const float2*)(kvh + (size_t)es[u].y * 128 + f0);
                }
                // ---- unconditional prefetch of next batch indices (pad16-safe) ----
                #pragma unroll
                for (int u = 0; u < 8; ++u) esn[u] = sorted2[t + 8 + u];
                // ---- logits ----
                float lgt[8]; float2 vfl[8];
                #pragma unroll
                for (int u = 0; u < 8; ++u) {
                    union { float2 f2; __half2 h2[2]; } uk; uk.f2 = kvraw[u];
                    float2 k0v0 = __half22float2(uk.h2[0]);
                    float2 k1v1 = __half22float2(uk.h2[1]);
                    vfl[u] = make_float2(k0v0.y, k1v1.y);
                    float part = qv.x * k0v0.x + qv.y * k1v1.x
                               + qev.x * efv[u][0] + qev.y * efv[u][1]
                               + qev.z * efv[u][2] + qev.w * efv[u][3];
                    part += __shfl_xor(part, 1);
                    part += __shfl_xor(part, 2);
                    part += __shfl_xor(part, 4);
                    lgt[u] = (u < cnt) ? (part * 0.25f + qbe25) : -1e30f;
                }
                // ---- batch tree combine ----
                float m01 = fmaxf(lgt[0], lgt[1]), m23 = fmaxf(lgt[2], lgt[3]);
                float m45 = fmaxf(lgt[4], lgt[5]), m67 = fmaxf(lgt[6], lgt[7]);
                float bm = fmaxf(fmaxf(m01, m23), fmaxf(m45, m67));
                float p[8];
                #pragma unroll
                for (int u = 0; u < 8; ++u) p[u] = __expf(lgt[u] - bm);
                float bsA = 0.f, bsB = 0.f, b0A = 0.f, b0B = 0.f, b1A = 0.f, b1B = 0.f;
                float4 befA = f4z(), befB = f4z();
                #pragma unroll
                for (int u = 0; u < 8; u += 2) {
                    bsA += p[u];     bsB += p[u + 1];
                    b0A = fmaf(p[u], vfl[u].x, b0A);       b0B = fmaf(p[u + 1], vfl[u + 1].x, b0B);
                    b1A = fmaf(p[u], vfl[u].y, b1A);       b1B = fmaf(p[u + 1], vfl[u + 1].y, b1B);
                    befA.x = fmaf(p[u], efv[u][0], befA.x); befB.x = fmaf(p[u + 1], efv[u + 1][0], befB.x);
                    befA.y = fmaf(p[u], efv[u][1], befA.y); befB.y = fmaf(p[u + 1], efv[u + 1][1], befB.y);
                    befA.z = fmaf(p[u], efv[u][2], befA.z); befB.z = fmaf(p[u + 1], efv[u + 1][2], befB.z);
                    befA.w = fmaf(p[u], efv[u][3], befA.w); befB.w = fmaf(p[u + 1], efv[u + 1][3], befB.w);
                }
                // ---- merge into running state ----
                const float nm = fmaxf(m, bm);
                const float so = __expf(m - nm);
                const float sn = __expf(bm - nm);
                s  = s  * so + (bsA + bsB) * sn;
                a0 = a0 * so + (b0A + b0B) * sn;
                a1 = a1 * so + (b1A + b1B) * sn;
                wef.x = wef.x * so + (befA.x + befB.x) * sn;
                wef.y = wef.y * so + (befA.y + befB.y) * sn;
                wef.z = wef.z * so + (befA.z + befB.z) * sn;
                wef.w = wef.w * so + (befA.w + befB.w) * sn;
                m = nm;
                #pragma unroll
                for (int u = 0; u < 8; ++u) es[u] = esn[u];
            }
        }

        const float inv = 1.f / (s + 1e-16f);
        float o0 = fmaf(a0, inv, be0);
        float o1 = fmaf(a1, inv, be1);
        float wn0 = wef.x * inv, wn1 = wef.y * inv, wn2 = wef.z * inv, wn3 = wef.w * inv;
        float ew0 = 0.f, ew1 = 0.f;
        #pragma unroll
        for (int l2 = 0; l2 < 8; ++l2) {
            float b0 = __shfl(wn0, grp + l2);
            float b1 = __shfl(wn1, grp + l2);
            float b2 = __shfl(wn2, grp + l2);
            float b3 = __shfl(wn3, grp + l2);
            float2 w0 = *(const float2*)&WeS[4 * l2 + 0][f0];
            float2 w1 = *(const float2*)&WeS[4 * l2 + 1][f0];
            float2 w2 = *(const float2*)&WeS[4 * l2 + 2][f0];
            float2 w3 = *(const float2*)&WeS[4 * l2 + 3][f0];
            ew0 += b0 * w0.x + b1 * w1.x + b2 * w2.x + b3 * w3.x;
            ew1 += b0 * w0.y + b1 * w1.y + b2 * w2.y + b3 * w3.y;
        }
        o0 += ew0; o1 += ew1;
        if (end == beg) { o0 = 0.f; o1 = 0.f; }

        const float2 xrv = *(const float2*)(xr + (size_t)node * 128 + f0);
        float bp = o0 * wbo0 + o1 * wbo1 + xrv.x * wbr0 + xrv.y * wbr1
                 + (o0 - xrv.x) * wbd0 + (o1 - xrv.y) * wbd1;
        #pragma unroll
        for (int msk = 1; msk < 64; msk <<= 1) bp += __shfl_xor(bp, msk);
        const float beta = 1.f / (1.f + __expf(-bp));
        const float2 xv = *(const float2*)(x + (size_t)node * 128 + f0);
        float t0 = beta * xrv.x + (1.f - beta) * o0 + xv.x;
        float t1 = beta * xrv.y + (1.f - beta) * o1 + xv.y;
        float sm = t0 + t1, sq = t0 * t0 + t1 * t1;
        #pragma unroll
        for (int msk = 1; msk < 64; msk <<= 1) { sm += __shfl_xor(sm, msk); sq += __shfl_xor(sq, msk); }
        const float mu = sm * (1.f / 128.f);
        const float var = sq * (1.f / 128.f) - mu * mu;
        const float rstd = rsqrtf(var + 1e-5f);
        const float h0 = fmaxf((t0 - mu) * rstd * lg0 + lb0, 0.f);
        const float h1 = fmaxf((t1 - mu) * rstd * lg1 + lb1, 0.f);
        *(float2*)(h + (size_t)node * 128 + f0) = make_float2(h0, h1);
        cs[wid][f0] += h0; cs[wid][f0 + 1] += h1;
    }
    __syncthreads();
    if (wid == 0) {
        float c0 = cs[0][f0] + cs[1][f0] + cs[2][f0] + cs[3][f0];
        float c1 = cs[0][f0 + 1] + cs[1][f0 + 1] + cs[2][f0 + 1] + cs[3][f0 + 1];
        atomicAdd(&colsum[f0], c0);
        atomicAdd(&colsum[f0 + 1], c1);
    }
}

// ---------------- global context ----------------

__global__ __launch_bounds__(1024) void gctx_kernel(
    const float* __restrict__ colsum,
    const float* __restrict__ Wr, const float* __restrict__ br,
    const float* __restrict__ Ww, const float* __restrict__ bw,
    const float* __restrict__ Wg, const float* __restrict__ bg,
    float* __restrict__ gc)
{
    __shared__ float hm[128], g[128], gb[128];
    __shared__ float red[8][128];
    const int t = threadIdx.x, f = t & 127, sl = t >> 7;
    if (sl == 0) hm[f] = colsum[f] * (1.f / (float)NN);
    __syncthreads();
    float a = 0.f;
    #pragma unroll
    for (int j = 0; j < 16; ++j) { int i = sl * 16 + j; a += hm[i] * Wr[i * 128 + f]; }
    red[sl][f] = a;
    __syncthreads();
    if (sl == 0) {
        float s = br[f];
        #pragma unroll
        for (int j = 0; j < 8; ++j) s += red[j][f];
        g[f] = fmaxf(s, 0.f);
    }
    __syncthreads();
    a = 0.f;
    #pragma unroll
    for (int j = 0; j < 16; ++j) { int i = sl * 16 + j; a += g[i] * Ww[i * 128 + f]; }
    red[sl][f] = a;
    __syncthreads();
    if (sl == 0) {
        float s = bw[f];
        #pragma unroll
        for (int j = 0; j < 8; ++j) s += red[j][f];
        gb[f] = s;
        gc[f] = s;
    }
    __syncthreads();
    a = 0.f;
    #pragma unroll
    for (int j = 0; j < 16; ++j) { int i = sl * 16 + j; a += gb[i] * Wg[(128 + i) * 128 + f]; }
    red[sl][f] = a;
    __syncthreads();
    if (sl == 0) {
        float s = bg[f];
        #pragma unroll
        for (int j = 0; j < 8; ++j) s += red[j][f];
        gc[128 + f] = s;
    }
}

// ---------------- final ----------------

__global__ __launch_bounds__(256) void final_kernel(
    const float* __restrict__ h, const float* __restrict__ Wg,
    const float* __restrict__ gc,
    const float* __restrict__ ln2g, const float* __restrict__ ln2b,
    float* __restrict__ out)
{
    __shared__ float hs[32][128];
    __shared__ float ys[32][128];
    const int tid = threadIdx.x;
    const int row0 = blockIdx.x * 32;
    for (int i = tid; i < 1024; i += 256) {
        int r = i >> 5, c4 = i & 31;
        int gr = row0 + r;
        float4 val = f4z();
        if (gr < NN) val = ((const float4*)(h + (size_t)gr * 128))[c4];
        ((float4*)hs[r])[c4] = val;
    }
    __syncthreads();
    const int cg = tid & 31;
    const int rg = tid >> 5;
    float4 a[4];
    #pragma unroll
    for (int r = 0; r < 4; ++r) a[r] = f4z();
    #pragma unroll 2
    for (int kk = 0; kk < 128; ++kk) {
        float4 w4 = ((const float4*)(Wg + kk * 128))[cg];
        #pragma unroll
        for (int r = 0; r < 4; ++r) {
            float xv = hs[4 * rg + r][kk];
            a[r].x += xv * w4.x; a[r].y += xv * w4.y; a[r].z += xv * w4.z; a[r].w += xv * w4.w;
        }
    }
    const float4 gb = ((const float4*)gc)[cg];
    const float4 c2 = ((const float4*)(gc + 128))[cg];
    #pragma unroll
    for (int r = 0; r < 4; ++r) {
        int row = 4 * rg + r;
        float4 hv = ((float4*)hs[row])[cg];
        float4 y;
        float gx;
        gx = 1.f / (1.f + __expf(-(a[r].x + c2.x))); y.x = hv.x + gx * gb.x;
        gx = 1.f / (1.f + __expf(-(a[r].y + c2.y))); y.y = hv.y + gx * gb.y;
        gx = 1.f / (1.f + __expf(-(a[r].z + c2.z))); y.z = hv.z + gx * gb.z;
        gx = 1.f / (1.f + __expf(-(a[r].w + c2.w))); y.w = hv.w + gx * gb.w;
        ((float4*)ys[row])[cg] = y;
    }
    __syncthreads();
    const int lane = tid & 63;
    const int wid = tid >> 6;
    const int f0 = 2 * lane;
    const float lg0 = ln2g[f0], lg1 = ln2g[f0 + 1];
    const float lb0 = ln2b[f0], lb1 = ln2b[f0 + 1];
    for (int rr = 0; rr < 8; ++rr) {
        int row = wid * 8 + rr;
        int gr = row0 + row;
        if (gr >= NN) continue;
        float y0 = ys[row][f0], y1 = ys[row][f0 + 1];
        float sm = y0 + y1, sq = y0 * y0 + y1 * y1;
        #pragma unroll
        for (int msk = 1; msk < 64; msk <<= 1) { sm += __shfl_xor(sm, msk); sq += __shfl_xor(sq, msk); }
        float mu = sm * (1.f / 128.f);
        float var = sq * (1.f / 128.f) - mu * mu;
        float rstd = rsqrtf(var + 1e-5f);
        float o0 = (y0 - mu) * rstd * lg0 + lb0;
        float o1 = (y1 - mu) * rstd * lg1 + lb1;
        *(float2*)(out + (size_t)gr * 128 + f0) = make_float2(o0, o1);
    }
}

// ---------------- launch ----------------

extern "C" void kernel_launch(void* const* d_in, const int* in_sizes, int n_in,
                              void* d_out, int out_size, void* d_ws, size_t ws_size,
                              hipStream_t stream)
{
    const float* x    = (const float*)d_in[0];
    const int*   ei   = (const int*)d_in[1];
    const float* ef   = (const float*)d_in[2];
    const float* Wq   = (const float*)d_in[3];
    const float* bq   = (const float*)d_in[4];
    const float* Wk   = (const float*)d_in[5];
    const float* bk   = (const float*)d_in[6];
    const float* Wv   = (const float*)d_in[7];
    const float* bv   = (const float*)d_in[8];
    const float* We   = (const float*)d_in[9];
    const float* be   = (const float*)d_in[10];
    const float* Wsk  = (const float*)d_in[11];
    const float* bsk  = (const float*)d_in[12];
    const float* Wbeta= (const float*)d_in[13];
    const float* g1   = (const float*)d_in[14];
    const float* b1   = (const float*)d_in[15];
    const float* Wr   = (const float*)d_in[16];
    const float* br   = (const float*)d_in[17];
    const float* Ww   = (const float*)d_in[18];
    const float* bw   = (const float*)d_in[19];
    const float* Wg   = (const float*)d_in[20];
    const float* bg   = (const float*)d_in[21];
    const float* g2   = (const float*)d_in[22];
    const float* b2   = (const float*)d_in[23];
    float* out = (float*)d_out;

    const size_t NF = (size_t)NN * 128;
    float* q      = (float*)d_ws;
    float* xr     = q + NF;
    float* h      = xr + NF;
    __half2* kvh  = (__half2*)(h + NF);       // NN*128 half2
    __half* qeh   = (__half*)(kvh + NF);      // NN*256 half
    float* colsum = (float*)(qeh + (size_t)NN * 256);
    float* gc     = colsum + 128;             // 256 floats
    int* counts   = (int*)(gc + 256);
    int* offsets  = counts + NN;              // NN+2 (pad)
    int* cursor   = offsets + NN + 2;
    int2* sorted2 = (int2*)(cursor + NN);     // EE+16 int2

    hipMemsetAsync(counts, 0, NN * sizeof(int), stream);
    hipMemsetAsync(colsum, 0, 128 * sizeof(float), stream);

    k1_kernel<<<NB_HIST + NB_PROJ, 256, 0, stream>>>(ei, counts, x,
        Wq, bq, Wk, bk, Wv, bv, Wsk, bsk, We, q, kvh, xr, qeh);
    scan_kernel<<<1, 1024, 0, stream>>>(counts, offsets, cursor);
    scatter_kernel<<<2048, 256, 0, stream>>>(ei, cursor, sorted2);
    attn_kernel<<<2048, 256, 0, stream>>>(ef, We, be, q, qeh, kvh, xr, x, Wbeta, g1, b1,
                                          offsets, sorted2, h, colsum);
    gctx_kernel<<<1, 1024, 0, stream>>>(colsum, Wr, br, Ww, bw, Wg, bg, gc);
    final_kernel<<<(NN + 31) / 32, 256, 0, stream>>>(h, Wg, gc, g2, b2, out);
}

// Round 8
// 732.947 us; speedup vs baseline: 1.2379x; 1.0091x over previous
//
#include <hip/hip_runtime.h>
#include <hip/hip_fp16.h>

#define NN 50000
#define EE 1600000
#define NB_HIST 1024
#define NB_PROJ 1563   // ceil(NN/32)

typedef float f4v __attribute__((ext_vector_type(4)));

static __device__ __forceinline__ float4 f4z() { return make_float4(0.f, 0.f, 0.f, 0.f); }

// ---------------- scan ----------------

__global__ __launch_bounds__(1024) void scan_kernel(const int* __restrict__ counts,
                                                    int* __restrict__ offsets,
                                                    int* __restrict__ cursor)
{
    __shared__ int wsum[16];
    __shared__ int wpre[16];
    __shared__ int carrys;
    const int t = threadIdx.x;
    const int lane = t & 63, wid = t >> 6;
    if (t == 0) carrys = 0;
    __syncthreads();
    for (int base = 0; base <= NN; base += 1024) {
        int i = base + t;
        int orig = (i < NN) ? counts[i] : 0;
        int val = orig;
        #pragma unroll
        for (int ofs = 1; ofs < 64; ofs <<= 1) {
            int n = __shfl_up(val, ofs);
            if (lane >= ofs) val += n;
        }
        if (lane == 63) wsum[wid] = val;
        __syncthreads();
        if (t < 16) {
            int w = wsum[t];
            #pragma unroll
            for (int ofs = 1; ofs < 16; ofs <<= 1) {
                int n = __shfl_up(w, ofs);
                if (t >= ofs) w += n;
            }
            wpre[t] = w;
        }
        __syncthreads();
        int carry = carrys;
        int incl = val + (wid ? wpre[wid - 1] : 0);
        int excl = incl - orig + carry;
        if (i < NN) { offsets[i] = excl; cursor[i] = excl; }
        else if (i == NN) offsets[NN] = excl;
        __syncthreads();
        if (t == 1023) carrys = carry + incl;
        __syncthreads();
    }
}

__global__ __launch_bounds__(256) void scatter_kernel(const int* __restrict__ ei,
                                                      int* __restrict__ cursor,
                                                      int2* __restrict__ sorted2)
{
    int i = blockIdx.x * blockDim.x + threadIdx.x;
    int stride = gridDim.x * blockDim.x;
    for (; i < EE; i += stride) {
        int srcn = ei[i];
        int d = ei[EE + i];
        int pos = atomicAdd(&cursor[d], 1);
        sorted2[pos] = make_int2(i, srcn);
    }
    if (blockIdx.x == 0 && threadIdx.x < 32) sorted2[EE + threadIdx.x] = make_int2(0, 0);
}

// ---------------- K1: hist (blocks < NB_HIST) + proj/qe (rest) ----------------

__global__ __launch_bounds__(256) void k1_kernel(
    const int* __restrict__ ei, int* __restrict__ counts,
    const float* __restrict__ x,
    const float* __restrict__ Wq, const float* __restrict__ bq,
    const float* __restrict__ Wk, const float* __restrict__ bk,
    const float* __restrict__ Wv, const float* __restrict__ bv,
    const float* __restrict__ Ws, const float* __restrict__ bs,
    const float* __restrict__ We,
    float* __restrict__ q, __half2* __restrict__ kvh,
    float* __restrict__ xr, __half* __restrict__ qeh)
{
    const int tid = threadIdx.x;
    if (blockIdx.x < NB_HIST) {
        int i = blockIdx.x * 256 + tid;
        int stride = NB_HIST * 256;
        for (; i < EE; i += stride) atomicAdd(&counts[ei[EE + i]], 1);
        return;
    }
    __shared__ float xs[32][132];
    __shared__ float WeS[32 * 129];
    const int row0 = (blockIdx.x - NB_HIST) * 32;
    for (int i = tid; i < 4096; i += 256) WeS[(i >> 7) * 129 + (i & 127)] = We[i];
    for (int i = tid; i < 1024; i += 256) {
        int r = i >> 5, c4 = i & 31;
        int gr = row0 + r;
        float4 val = f4z();
        if (gr < NN) val = ((const float4*)(x + (size_t)gr * 128))[c4];
        ((float4*)xs[r])[c4] = val;
    }
    __syncthreads();
    const int cg = tid & 31;
    const int rg = tid >> 5;
    float4 aq[4], ak[4], av[4], as_[4];
    #pragma unroll
    for (int r = 0; r < 4; ++r) { aq[r] = f4z(); ak[r] = f4z(); av[r] = f4z(); as_[r] = f4z(); }
    #pragma unroll 2
    for (int kk = 0; kk < 128; ++kk) {
        float4 wq = ((const float4*)(Wq + kk * 128))[cg];
        float4 wk = ((const float4*)(Wk + kk * 128))[cg];
        float4 wv = ((const float4*)(Wv + kk * 128))[cg];
        float4 ws = ((const float4*)(Ws + kk * 128))[cg];
        #pragma unroll
        for (int r = 0; r < 4; ++r) {
            float xv = xs[4 * rg + r][kk];
            aq[r].x += xv * wq.x; aq[r].y += xv * wq.y; aq[r].z += xv * wq.z; aq[r].w += xv * wq.w;
            ak[r].x += xv * wk.x; ak[r].y += xv * wk.y; ak[r].z += xv * wk.z; ak[r].w += xv * wk.w;
            av[r].x += xv * wv.x; av[r].y += xv * wv.y; av[r].z += xv * wv.z; av[r].w += xv * wv.w;
            as_[r].x += xv * ws.x; as_[r].y += xv * ws.y; as_[r].z += xv * ws.z; as_[r].w += xv * ws.w;
        }
    }
    const float4 bq4 = ((const float4*)bq)[cg];
    const float4 bk4 = ((const float4*)bk)[cg];
    const float4 bv4 = ((const float4*)bv)[cg];
    const float4 bs4 = ((const float4*)bs)[cg];
    __syncthreads();   // all GEMM reads of xs done before q overwrites it
    #pragma unroll
    for (int r = 0; r < 4; ++r) {
        int gr = row0 + 4 * rg + r;
        if (gr >= NN) continue;
        float4 o;
        o.x = aq[r].x + bq4.x; o.y = aq[r].y + bq4.y; o.z = aq[r].z + bq4.z; o.w = aq[r].w + bq4.w;
        ((float4*)(q + (size_t)gr * 128))[cg] = o;
        ((float4*)xs[4 * rg + r])[cg] = o;    // stash q tile for qe phase
        float kx = ak[r].x + bk4.x, ky = ak[r].y + bk4.y, kz = ak[r].z + bk4.z, kw = ak[r].w + bk4.w;
        float vx = av[r].x + bv4.x, vy = av[r].y + bv4.y, vz = av[r].z + bv4.z, vw = av[r].w + bv4.w;
        union { __half2 h2[4]; float4 f4; } up;
        up.h2[0] = __floats2half2_rn(kx, vx);
        up.h2[1] = __floats2half2_rn(ky, vy);
        up.h2[2] = __floats2half2_rn(kz, vz);
        up.h2[3] = __floats2half2_rn(kw, vw);
        *((float4*)(kvh + (size_t)gr * 128 + 4 * cg)) = up.f4;
        o.x = as_[r].x + bs4.x; o.y = as_[r].y + bs4.y; o.z = as_[r].z + bs4.z; o.w = as_[r].w + bs4.w;
        ((float4*)(xr + (size_t)gr * 128))[cg] = o;
    }
    __syncthreads();
    // qe phase: qe[n, h*32+d] = sum_c q[n, h*16+c] * We[d, h*16+c]
    const int row = tid >> 3;      // 0..31
    const int j = tid & 7;         // 0..7 -> d = j*4..j*4+3
    const int gr2 = row0 + row;
    if (gr2 < NN) {
        const float* xrow = xs[row];
        #pragma unroll
        for (int hh = 0; hh < 8; ++hh) {
            float a0 = 0.f, a1 = 0.f, a2 = 0.f, a3 = 0.f;
            #pragma unroll
            for (int c = 0; c < 16; ++c) {
                float qv = xrow[hh * 16 + c];
                const float* wb = &WeS[(j * 4) * 129 + hh * 16 + c];
                a0 += qv * wb[0];
                a1 += qv * wb[129];
                a2 += qv * wb[258];
                a3 += qv * wb[387];
            }
            union { __half2 h2[2]; unsigned long long u64; } u;
            u.h2[0] = __floats2half2_rn(a0, a1);
            u.h2[1] = __floats2half2_rn(a2, a3);
            *(unsigned long long*)(qeh + (size_t)gr2 * 256 + hh * 32 + j * 4) = u.u64;
        }
    }
}

// ---------------- fused attention + beta-skip + LN1 + relu ----------------
// one wave/node; 8-edge batches; data gathers software-pipelined 1 batch ahead.

__global__ __launch_bounds__(256) void attn_kernel(
    const float* __restrict__ efeat,
    const float* __restrict__ We, const float* __restrict__ be,
    const float* __restrict__ q, const __half* __restrict__ qeh,
    const __half2* __restrict__ kvh,
    const float* __restrict__ xr, const float* __restrict__ x,
    const float* __restrict__ Wbeta,
    const float* __restrict__ ln1g, const float* __restrict__ ln1b,
    const int* __restrict__ offsets, const int2* __restrict__ sorted2,
    float* __restrict__ h, float* __restrict__ colsum)
{
    __shared__ float WeS[32][128];
    __shared__ float cs[4][128];
    const int tid = threadIdx.x;
    for (int i = tid; i < 4096; i += 256) ((float*)WeS)[i] = We[i];
    const int lane = tid & 63;
    const int wid = tid >> 6;
    const int f0 = 2 * lane;
    const int l8 = lane & 7;
    const int grp = lane & 56;

    const float be0 = be[f0], be1 = be[f0 + 1];
    const float wbo0 = Wbeta[f0],       wbo1 = Wbeta[f0 + 1];
    const float wbr0 = Wbeta[128 + f0], wbr1 = Wbeta[128 + f0 + 1];
    const float wbd0 = Wbeta[256 + f0], wbd1 = Wbeta[256 + f0 + 1];
    const float lg0 = ln1g[f0], lg1 = ln1g[f0 + 1];
    const float lb0 = ln1b[f0], lb1 = ln1b[f0 + 1];

    cs[wid][f0] = 0.f; cs[wid][f0 + 1] = 0.f;
    __syncthreads();

    const int gwave = blockIdx.x * 4 + wid;
    const int nwave = gridDim.x * 4;

    for (int node = gwave; node < NN; node += nwave) {
        const int beg = offsets[node];
        const int end = offsets[node + 1];
        const float2 qv = *(const float2*)(q + (size_t)node * 128 + f0);
        union { float2 f2; __half2 h2[2]; } uq;
        uq.f2 = *(const float2*)(qeh + (size_t)node * 256 + 4 * lane);
        const float2 qe01 = __half22float2(uq.h2[0]);
        const float2 qe23 = __half22float2(uq.h2[1]);
        const float4 qev = make_float4(qe01.x, qe01.y, qe23.x, qe23.y);
        float qbe = qv.x * be0 + qv.y * be1;
        qbe += __shfl_xor(qbe, 1); qbe += __shfl_xor(qbe, 2); qbe += __shfl_xor(qbe, 4);
        const float qbe25 = qbe * 0.25f;

        float m = -1e30f, s = 0.f, a0 = 0.f, a1 = 0.f;
        float4 wef = f4z();

        if (beg < end) {
            int2 esA[8], esB[8];
            f4v efA[8], efB[8];
            float2 kvA[8], kvB[8];

            // prologue: idx(t0) -> data(t0) -> idx(t1)
            #pragma unroll
            for (int u = 0; u < 8; ++u) esA[u] = sorted2[beg + u];
            #pragma unroll
            for (int u = 0; u < 8; ++u) {
                efA[u] = __builtin_nontemporal_load(
                    (const f4v*)(efeat + (size_t)esA[u].x * 32 + 4 * l8));
                kvA[u] = *(const float2*)(kvh + (size_t)esA[u].y * 128 + f0);
            }
            #pragma unroll
            for (int u = 0; u < 8; ++u) esB[u] = sorted2[beg + 8 + u];

            // one pipeline phase: issue data(t+8) via idxN, prefetch idx(t+16)
            // into idxF, compute batch t from efC/kvC.
            auto phase = [&](f4v (&efC)[8], float2 (&kvC)[8],
                             f4v (&efN)[8], float2 (&kvN)[8],
                             int2 (&idxN)[8], int2 (&idxF)[8], int t) {
                #pragma unroll
                for (int u = 0; u < 8; ++u) {
                    efN[u] = __builtin_nontemporal_load(
                        (const f4v*)(efeat + (size_t)idxN[u].x * 32 + 4 * l8));
                    kvN[u] = *(const float2*)(kvh + (size_t)idxN[u].y * 128 + f0);
                }
                #pragma unroll
                for (int u = 0; u < 8; ++u) idxF[u] = sorted2[t + 16 + u];

                const int cnt = end - t;
                float lgt[8]; float2 vfl[8];
                #pragma unroll
                for (int u = 0; u < 8; ++u) {
                    union { float2 f2; __half2 h2[2]; } uk; uk.f2 = kvC[u];
                    float2 k0v0 = __half22float2(uk.h2[0]);
                    float2 k1v1 = __half22float2(uk.h2[1]);
                    vfl[u] = make_float2(k0v0.y, k1v1.y);
                    float part = qv.x * k0v0.x + qv.y * k1v1.x
                               + qev.x * efC[u][0] + qev.y * efC[u][1]
                               + qev.z * efC[u][2] + qev.w * efC[u][3];
                    part += __shfl_xor(part, 1);
                    part += __shfl_xor(part, 2);
                    part += __shfl_xor(part, 4);
                    lgt[u] = (u < cnt) ? (part * 0.25f + qbe25) : -1e30f;
                }
                float m01 = fmaxf(lgt[0], lgt[1]), m23 = fmaxf(lgt[2], lgt[3]);
                float m45 = fmaxf(lgt[4], lgt[5]), m67 = fmaxf(lgt[6], lgt[7]);
                float bm = fmaxf(fmaxf(m01, m23), fmaxf(m45, m67));
                float p[8];
                #pragma unroll
                for (int u = 0; u < 8; ++u) p[u] = __expf(lgt[u] - bm);
                float bsA = 0.f, bsB = 0.f, b0A = 0.f, b0B = 0.f, b1A = 0.f, b1B = 0.f;
                float4 befA = f4z(), befB = f4z();
                #pragma unroll
                for (int u = 0; u < 8; u += 2) {
                    bsA += p[u];     bsB += p[u + 1];
                    b0A = fmaf(p[u], vfl[u].x, b0A);        b0B = fmaf(p[u + 1], vfl[u + 1].x, b0B);
                    b1A = fmaf(p[u], vfl[u].y, b1A);        b1B = fmaf(p[u + 1], vfl[u + 1].y, b1B);
                    befA.x = fmaf(p[u], efC[u][0], befA.x); befB.x = fmaf(p[u + 1], efC[u + 1][0], befB.x);
                    befA.y = fmaf(p[u], efC[u][1], befA.y); befB.y = fmaf(p[u + 1], efC[u + 1][1], befB.y);
                    befA.z = fmaf(p[u], efC[u][2], befA.z); befB.z = fmaf(p[u + 1], efC[u + 1][2], befB.z);
                    befA.w = fmaf(p[u], efC[u][3], befA.w); befB.w = fmaf(p[u + 1], efC[u + 1][3], befB.w);
                }
                const float nm = fmaxf(m, bm);
                const float so = __expf(m - nm);
                const float sn = __expf(bm - nm);
                s  = s  * so + (bsA + bsB) * sn;
                a0 = a0 * so + (b0A + b0B) * sn;
                a1 = a1 * so + (b1A + b1B) * sn;
                wef.x = wef.x * so + (befA.x + befB.x) * sn;
                wef.y = wef.y * so + (befA.y + befB.y) * sn;
                wef.z = wef.z * so + (befA.z + befB.z) * sn;
                wef.w = wef.w * so + (befA.w + befB.w) * sn;
                m = nm;
            };

            int t = beg;
            while (true) {
                phase(efA, kvA, efB, kvB, esB, esA, t); t += 8; if (t >= end) break;
                phase(efB, kvB, efA, kvA, esA, esB, t); t += 8; if (t >= end) break;
            }
        }

        const float inv = 1.f / (s + 1e-16f);
        float o0 = fmaf(a0, inv, be0);
        float o1 = fmaf(a1, inv, be1);
        float wn0 = wef.x * inv, wn1 = wef.y * inv, wn2 = wef.z * inv, wn3 = wef.w * inv;
        float ew0 = 0.f, ew1 = 0.f;
        #pragma unroll
        for (int l2 = 0; l2 < 8; ++l2) {
            float b0 = __shfl(wn0, grp + l2);
            float b1 = __shfl(wn1, grp + l2);
            float b2 = __shfl(wn2, grp + l2);
            float b3 = __shfl(wn3, grp + l2);
            float2 w0 = *(const float2*)&WeS[4 * l2 + 0][f0];
            float2 w1 = *(const float2*)&WeS[4 * l2 + 1][f0];
            float2 w2 = *(const float2*)&WeS[4 * l2 + 2][f0];
            float2 w3 = *(const float2*)&WeS[4 * l2 + 3][f0];
            ew0 += b0 * w0.x + b1 * w1.x + b2 * w2.x + b3 * w3.x;
            ew1 += b0 * w0.y + b1 * w1.y + b2 * w2.y + b3 * w3.y;
        }
        o0 += ew0; o1 += ew1;
        if (end == beg) { o0 = 0.f; o1 = 0.f; }

        const float2 xrv = *(const float2*)(xr + (size_t)node * 128 + f0);
        float bp = o0 * wbo0 + o1 * wbo1 + xrv.x * wbr0 + xrv.y * wbr1
                 + (o0 - xrv.x) * wbd0 + (o1 - xrv.y) * wbd1;
        #pragma unroll
        for (int msk = 1; msk < 64; msk <<= 1) bp += __shfl_xor(bp, msk);
        const float beta = 1.f / (1.f + __expf(-bp));
        const float2 xv = *(const float2*)(x + (size_t)node * 128 + f0);
        float t0 = beta * xrv.x + (1.f - beta) * o0 + xv.x;
        float t1 = beta * xrv.y + (1.f - beta) * o1 + xv.y;
        float sm = t0 + t1, sq = t0 * t0 + t1 * t1;
        #pragma unroll
        for (int msk = 1; msk < 64; msk <<= 1) { sm += __shfl_xor(sm, msk); sq += __shfl_xor(sq, msk); }
        const float mu = sm * (1.f / 128.f);
        const float var = sq * (1.f / 128.f) - mu * mu;
        const float rstd = rsqrtf(var + 1e-5f);
        const float h0 = fmaxf((t0 - mu) * rstd * lg0 + lb0, 0.f);
        const float h1 = fmaxf((t1 - mu) * rstd * lg1 + lb1, 0.f);
        *(float2*)(h + (size_t)node * 128 + f0) = make_float2(h0, h1);
        cs[wid][f0] += h0; cs[wid][f0 + 1] += h1;
    }
    __syncthreads();
    if (wid == 0) {
        float c0 = cs[0][f0] + cs[1][f0] + cs[2][f0] + cs[3][f0];
        float c1 = cs[0][f0 + 1] + cs[1][f0 + 1] + cs[2][f0 + 1] + cs[3][f0 + 1];
        atomicAdd(&colsum[f0], c0);
        atomicAdd(&colsum[f0 + 1], c1);
    }
}

// ---------------- global context ----------------

__global__ __launch_bounds__(1024) void gctx_kernel(
    const float* __restrict__ colsum,
    const float* __restrict__ Wr, const float* __restrict__ br,
    const float* __restrict__ Ww, const float* __restrict__ bw,
    const float* __restrict__ Wg, const float* __restrict__ bg,
    float* __restrict__ gc)
{
    __shared__ float hm[128], g[128], gb[128];
    __shared__ float red[8][128];
    const int t = threadIdx.x, f = t & 127, sl = t >> 7;
    if (sl == 0) hm[f] = colsum[f] * (1.f / (float)NN);
    __syncthreads();
    float a = 0.f;
    #pragma unroll
    for (int j = 0; j < 16; ++j) { int i = sl * 16 + j; a += hm[i] * Wr[i * 128 + f]; }
    red[sl][f] = a;
    __syncthreads();
    if (sl == 0) {
        float s = br[f];
        #pragma unroll
        for (int j = 0; j < 8; ++j) s += red[j][f];
        g[f] = fmaxf(s, 0.f);
    }
    __syncthreads();
    a = 0.f;
    #pragma unroll
    for (int j = 0; j < 16; ++j) { int i = sl * 16 + j; a += g[i] * Ww[i * 128 + f]; }
    red[sl][f] = a;
    __syncthreads();
    if (sl == 0) {
        float s = bw[f];
        #pragma unroll
        for (int j = 0; j < 8; ++j) s += red[j][f];
        gb[f] = s;
        gc[f] = s;
    }
    __syncthreads();
    a = 0.f;
    #pragma unroll
    for (int j = 0; j < 16; ++j) { int i = sl * 16 + j; a += gb[i] * Wg[(128 + i) * 128 + f]; }
    red[sl][f] = a;
    __syncthreads();
    if (sl == 0) {
        float s = bg[f];
        #pragma unroll
        for (int j = 0; j < 8; ++j) s += red[j][f];
        gc[128 + f] = s;
    }
}

// ---------------- final ----------------

__global__ __launch_bounds__(256) void final_kernel(
    const float* __restrict__ h, const float* __restrict__ Wg,
    const float* __restrict__ gc,
    const float* __restrict__ ln2g, const float* __restrict__ ln2b,
    float* __restrict__ out)
{
    __shared__ float hs[32][128];
    __shared__ float ys[32][128];
    const int tid = threadIdx.x;
    const int row0 = blockIdx.x * 32;
    for (int i = tid; i < 1024; i += 256) {
        int r = i >> 5, c4 = i & 31;
        int gr = row0 + r;
        float4 val = f4z();
        if (gr < NN) val = ((const float4*)(h + (size_t)gr * 128))[c4];
        ((float4*)hs[r])[c4] = val;
    }
    __syncthreads();
    const int cg = tid & 31;
    const int rg = tid >> 5;
    float4 a[4];
    #pragma unroll
    for (int r = 0; r < 4; ++r) a[r] = f4z();
    #pragma unroll 2
    for (int kk = 0; kk < 128; ++kk) {
        float4 w4 = ((const float4*)(Wg + kk * 128))[cg];
        #pragma unroll
        for (int r = 0; r < 4; ++r) {
            float xv = hs[4 * rg + r][kk];
            a[r].x += xv * w4.x; a[r].y += xv * w4.y; a[r].z += xv * w4.z; a[r].w += xv * w4.w;
        }
    }
    const float4 gb = ((const float4*)gc)[cg];
    const float4 c2 = ((const float4*)(gc + 128))[cg];
    #pragma unroll
    for (int r = 0; r < 4; ++r) {
        int row = 4 * rg + r;
        float4 hv = ((float4*)hs[row])[cg];
        float4 y;
        float gx;
        gx = 1.f / (1.f + __expf(-(a[r].x + c2.x))); y.x = hv.x + gx * gb.x;
        gx = 1.f / (1.f + __expf(-(a[r].y + c2.y))); y.y = hv.y + gx * gb.y;
        gx = 1.f / (1.f + __expf(-(a[r].z + c2.z))); y.z = hv.z + gx * gb.z;
        gx = 1.f / (1.f + __expf(-(a[r].w + c2.w))); y.w = hv.w + gx * gb.w;
        ((float4*)ys[row])[cg] = y;
    }
    __syncthreads();
    const int lane = tid & 63;
    const int wid = tid >> 6;
    const int f0 = 2 * lane;
    const float lg0 = ln2g[f0], lg1 = ln2g[f0 + 1];
    const float lb0 = ln2b[f0], lb1 = ln2b[f0 + 1];
    for (int rr = 0; rr < 8; ++rr) {
        int row = wid * 8 + rr;
        int gr = row0 + row;
        if (gr >= NN) continue;
        float y0 = ys[row][f0], y1 = ys[row][f0 + 1];
        float sm = y0 + y1, sq = y0 * y0 + y1 * y1;
        #pragma unroll
        for (int msk = 1; msk < 64; msk <<= 1) { sm += __shfl_xor(sm, msk); sq += __shfl_xor(sq, msk); }
        float mu = sm * (1.f / 128.f);
        float var = sq * (1.f / 128.f) - mu * mu;
        float rstd = rsqrtf(var + 1e-5f);
        float o0 = (y0 - mu) * rstd * lg0 + lb0;
        float o1 = (y1 - mu) * rstd * lg1 + lb1;
        *(float2*)(out + (size_t)gr * 128 + f0) = make_float2(o0, o1);
    }
}

// ---------------- launch ----------------

extern "C" void kernel_launch(void* const* d_in, const int* in_sizes, int n_in,
                              void* d_out, int out_size, void* d_ws, size_t ws_size,
                              hipStream_t stream)
{
    const float* x    = (const float*)d_in[0];
    const int*   ei   = (const int*)d_in[1];
    const float* ef   = (const float*)d_in[2];
    const float* Wq   = (const float*)d_in[3];
    const float* bq   = (const float*)d_in[4];
    const float* Wk   = (const float*)d_in[5];
    const float* bk   = (const float*)d_in[6];
    const float* Wv   = (const float*)d_in[7];
    const float* bv   = (const float*)d_in[8];
    const float* We   = (const float*)d_in[9];
    const float* be   = (const float*)d_in[10];
    const float* Wsk  = (const float*)d_in[11];
    const float* bsk  = (const float*)d_in[12];
    const float* Wbeta= (const float*)d_in[13];
    const float* g1   = (const float*)d_in[14];
    const float* b1   = (const float*)d_in[15];
    const float* Wr   = (const float*)d_in[16];
    const float* br   = (const float*)d_in[17];
    const float* Ww   = (const float*)d_in[18];
    const float* bw   = (const float*)d_in[19];
    const float* Wg   = (const float*)d_in[20];
    const float* bg   = (const float*)d_in[21];
    const float* g2   = (const float*)d_in[22];
    const float* b2   = (const float*)d_in[23];
    float* out = (float*)d_out;

    const size_t NF = (size_t)NN * 128;
    float* q      = (float*)d_ws;
    float* xr     = q + NF;
    float* h      = xr + NF;
    __half2* kvh  = (__half2*)(h + NF);       // NN*128 half2
    __half* qeh   = (__half*)(kvh + NF);      // NN*256 half
    float* colsum = (float*)(qeh + (size_t)NN * 256);
    float* gc     = colsum + 128;             // 256 floats
    int* counts   = (int*)(gc + 256);
    int* offsets  = counts + NN;              // NN+2 (pad)
    int* cursor   = offsets + NN + 2;
    int2* sorted2 = (int2*)(cursor + NN);     // EE+32 int2

    hipMemsetAsync(counts, 0, NN * sizeof(int), stream);
    hipMemsetAsync(colsum, 0, 128 * sizeof(float), stream);

    k1_kernel<<<NB_HIST + NB_PROJ, 256, 0, stream>>>(ei, counts, x,
        Wq, bq, Wk, bk, Wv, bv, Wsk, bsk, We, q, kvh, xr, qeh);
    scan_kernel<<<1, 1024, 0, stream>>>(counts, offsets, cursor);
    scatter_kernel<<<2048, 256, 0, stream>>>(ei, cursor, sorted2);
    attn_kernel<<<2048, 256, 0, stream>>>(ef, We, be, q, qeh, kvh, xr, x, Wbeta, g1, b1,
                                          offsets, sorted2, h, colsum);
    gctx_kernel<<<1, 1024, 0, stream>>>(colsum, Wr, br, Ww, bw, Wg, bg, gc);
    final_kernel<<<(NN + 31) / 32, 256, 0, stream>>>(h, Wg, gc, g2, b2, out);
}